// Round 4
// baseline (690.865 us; speedup 1.0000x reference)
//
#include <hip/hip_runtime.h>

#define N_NODES 100000
#define N_EDGES 1600000
#define ET      (N_EDGES + N_NODES)   // edges + self-loops = 1,700,000
#define NG      512
#define SLOPE   0.2f
#define NB_SCAN ((N_NODES + 511) / 512)   // 196 scan blocks

// ---------------- layer 1: h1 = x @ W1, attention logits ----------------
__global__ __launch_bounds__(256) void k_h1(
    const float* __restrict__ x, const float* __restrict__ W1,
    const float* __restrict__ a1s, const float* __restrict__ a1d,
    float* __restrict__ h1, float* __restrict__ al1s, float* __restrict__ al1d)
{
    __shared__ float Wl[64 * 64];
    __shared__ float xs[4][64];
    __shared__ float hs[4][64];
    int tid = threadIdx.x;
    for (int i = tid; i < 64 * 64; i += 256) Wl[i] = W1[i];
    int n = tid >> 6, c = tid & 63;
    int node = blockIdx.x * 4 + n;
    xs[n][c] = x[node * 64 + c];
    __syncthreads();
    float acc = 0.f;
#pragma unroll
    for (int k = 0; k < 64; ++k) acc = fmaf(xs[n][k], Wl[k * 64 + c], acc);
    h1[node * 64 + c] = acc;
    hs[n][c] = acc;
    __syncthreads();
    if (tid < 16) {
        int n2 = tid >> 2, h = tid & 3;
        int node2 = blockIdx.x * 4 + n2;
        float s = 0.f, d = 0.f;
#pragma unroll
        for (int j = 0; j < 16; ++j) {
            float v = hs[n2][h * 16 + j];
            s = fmaf(v, a1s[h * 16 + j], s);
            d = fmaf(v, a1d[h * 16 + j], d);
        }
        al1s[node2 * 4 + h] = s;
        al1d[node2 * 4 + h] = d;
    }
}

// ---------------- CSR build ----------------
__global__ __launch_bounds__(256) void k_hist(const int* __restrict__ ei, int* __restrict__ deg)
{
    int eid = blockIdx.x * 256 + threadIdx.x;
    if (eid >= ET) return;
    int d = (eid < N_EDGES) ? ei[N_EDGES + eid] : (eid - N_EDGES);
    atomicAdd(&deg[d], 1);
}

__global__ __launch_bounds__(512) void k_scan1(const int* __restrict__ deg,
                                               int* __restrict__ part, int* __restrict__ bsum)
{
    __shared__ int tmp[512];
    int i = blockIdx.x * 512 + threadIdx.x;
    int v = (i < N_NODES) ? deg[i] : 0;
    tmp[threadIdx.x] = v;
    __syncthreads();
    for (int off = 1; off < 512; off <<= 1) {
        int t = (threadIdx.x >= off) ? tmp[threadIdx.x - off] : 0;
        __syncthreads();
        tmp[threadIdx.x] += t;
        __syncthreads();
    }
    if (i < N_NODES) part[i] = tmp[threadIdx.x] - v;
    if (threadIdx.x == 511) bsum[blockIdx.x] = tmp[511];
}

__global__ __launch_bounds__(256) void k_scan2(int* __restrict__ bsum)
{
    __shared__ int tmp[256];
    int tid = threadIdx.x;
    int v = (tid < NB_SCAN) ? bsum[tid] : 0;
    tmp[tid] = v;
    __syncthreads();
    for (int off = 1; off < 256; off <<= 1) {
        int t = (tid >= off) ? tmp[tid - off] : 0;
        __syncthreads();
        tmp[tid] += t;
        __syncthreads();
    }
    if (tid < NB_SCAN) bsum[tid] = tmp[tid] - v;
}

__global__ __launch_bounds__(512) void k_scan3(const int* __restrict__ part,
                                               const int* __restrict__ bsum,
                                               int* __restrict__ offs, int* __restrict__ cursor)
{
    int i = blockIdx.x * 512 + threadIdx.x;
    if (i >= N_NODES) return;
    int o = part[i] + bsum[blockIdx.x];
    offs[i] = o;
    cursor[i] = o;
}

__global__ __launch_bounds__(256) void k_scatter(const int* __restrict__ ei,
                                                 int* __restrict__ cursor, int* __restrict__ csr)
{
    int eid = blockIdx.x * 256 + threadIdx.x;
    if (eid >= ET) return;
    int s, d;
    if (eid < N_EDGES) { s = ei[eid]; d = ei[N_EDGES + eid]; }
    else               { s = eid - N_EDGES; d = s; }
    int pos = atomicAdd(&cursor[d], 1);
    csr[pos] = s;
}

// ---- layer 1 aggregate (1 wave/dst, batch-8 pipelined gathers) ----
__global__ __launch_bounds__(256) void k_agg1(
    const int* __restrict__ offs, const int* __restrict__ deg, const int* __restrict__ csr,
    const float* __restrict__ h1, const float* __restrict__ al1s, const float* __restrict__ al1d,
    const float* __restrict__ b1, const float* __restrict__ W2,
    const float* __restrict__ a2s, const float* __restrict__ a2d,
    float* __restrict__ h2, float* __restrict__ al2s, float* __restrict__ al2d)
{
    __shared__ float W2l[64 * 16];
    __shared__ int   sarr[4][64];
    __shared__ float warr[4][4][72];    // [wave][head][j], 72-stride: conflict-free
    __shared__ float h1b[4][64];
    __shared__ float h2s[4][16];
    int tid = threadIdx.x;
    for (int i = tid; i < 64 * 16; i += 256) W2l[i] = W2[i];
    __syncthreads();                    // only barrier: W2l is cross-wave

    int wv = tid >> 6, lane = tid & 63;
    int c = lane, h = lane >> 4;
    int node = blockIdx.x * 4 + wv;
    int st = offs[node], dg = deg[node];
    const float4 ald4 = *(const float4*)(al1d + node * 4);

    float acc = 0.f, den = 0.f;
    for (int base = 0; base < dg; base += 64) {
        int m = min(64, dg - base);
        int m_pad = (m + 7) & ~7;
        int s = 0;
        float w0 = 0.f, w1 = 0.f, w2 = 0.f, w3 = 0.f;
        if (lane < m) {
            s = csr[st + base + lane];              // coalesced
            const float4 as4 = *(const float4*)(al1s + s * 4);
            float e0 = as4.x + ald4.x; e0 = e0 > 0.f ? e0 : SLOPE * e0;
            float e1 = as4.y + ald4.y; e1 = e1 > 0.f ? e1 : SLOPE * e1;
            float e2 = as4.z + ald4.z; e2 = e2 > 0.f ? e2 : SLOPE * e2;
            float e3 = as4.w + ald4.w; e3 = e3 > 0.f ? e3 : SLOPE * e3;
            w0 = __expf(e0); w1 = __expf(e1); w2 = __expf(e2); w3 = __expf(e3);
        }
        sarr[wv][lane] = s;                         // pad lanes: s=0, w=0
        warr[wv][0][lane] = w0;
        warr[wv][1][lane] = w1;
        warr[wv][2][lane] = w2;
        warr[wv][3][lane] = w3;
        // intra-wave LDS dependency only — no barrier needed
        for (int j0 = 0; j0 < m_pad; j0 += 8) {
            int   ss[8];
            float ww[8], vv[8];
#pragma unroll
            for (int k = 0; k < 8; ++k) {
                ss[k] = sarr[wv][j0 + k];           // broadcast
                ww[k] = warr[wv][h][j0 + k];        // broadcast per head
            }
#pragma unroll
            for (int k = 0; k < 8; ++k)
                vv[k] = h1[ss[k] * 64 + c];         // 8 independent 256B gathers
#pragma unroll
            for (int k = 0; k < 8; ++k) {
                acc = fmaf(ww[k], vv[k], acc);
                den += ww[k];
            }
        }
    }
    float v = acc / (den + 1e-16f) + b1[c];
    v = v > 0.f ? v : expm1f(v);        // ELU
    h1b[wv][c] = v;
    // intra-wave: no barrier needed
    if (c < 16) {
        float a = 0.f;
#pragma unroll
        for (int k = 0; k < 64; ++k) a = fmaf(h1b[wv][k], W2l[k * 16 + c], a);
        h2[node * 16 + c] = a;
        h2s[wv][c] = a;
    }
    if (c == 0) {
        float s2 = 0.f, d2 = 0.f;
#pragma unroll
        for (int j = 0; j < 16; ++j) {
            float v2 = h2s[wv][j];
            s2 = fmaf(v2, a2s[j], s2);
            d2 = fmaf(v2, a2d[j], d2);
        }
        al2s[node] = s2;
        al2d[node] = d2;
    }
}

// ---- layer 2 aggregate (1 wave/dst, 4 edges x 16 ch, pipelined) ----
__global__ __launch_bounds__(256) void k_agg2(
    const int* __restrict__ offs, const int* __restrict__ deg, const int* __restrict__ csr,
    const float* __restrict__ h2, const float* __restrict__ al2s, const float* __restrict__ al2d,
    const float* __restrict__ b2, const int* __restrict__ batch,
    float* __restrict__ pooled, float* __restrict__ counts)
{
    __shared__ int   sarr[4][64];
    __shared__ float warr[4][64];
    int tid = threadIdx.x;
    int wv = tid >> 6, lane = tid & 63;
    int sub = lane >> 4, c = lane & 15;
    int node = blockIdx.x * 4 + wv;
    int st = offs[node], dg = deg[node];
    float ald = al2d[node];

    float acc0 = 0.f, acc1 = 0.f, den = 0.f;
    for (int base = 0; base < dg; base += 64) {
        int m = min(64, dg - base);
        int m_pad = (m + 7) & ~7;
        int s = 0; float wl = 0.f;
        if (lane < m) {
            s = csr[st + base + lane];              // coalesced
            float e = al2s[s] + ald;                // 64 independent gathers
            e = e > 0.f ? e : SLOPE * e;
            wl = __expf(e);
        }
        sarr[wv][lane] = s;                         // pad: s=0, w=0
        warr[wv][lane] = wl;
        float t = wl;
        t += __shfl_xor(t, 1);  t += __shfl_xor(t, 2);
        t += __shfl_xor(t, 4);  t += __shfl_xor(t, 8);
        t += __shfl_xor(t, 16); t += __shfl_xor(t, 32);
        den += t;
#pragma unroll 2
        for (int j0 = 0; j0 < m_pad; j0 += 8) {
            int   sA = sarr[wv][j0 + sub],     sB = sarr[wv][j0 + 4 + sub];
            float wA = warr[wv][j0 + sub],     wB = warr[wv][j0 + 4 + sub];
            float vA = h2[sA * 16 + c],        vB = h2[sB * 16 + c];
            acc0 = fmaf(wA, vA, acc0);
            acc1 = fmaf(wB, vB, acc1);
        }
    }
    float acc = acc0 + acc1;
    acc += __shfl_xor(acc, 16); acc += __shfl_xor(acc, 32);
    if (sub == 0) {
        float v = acc / (den + 1e-16f) + b2[c];
        v = v > 0.f ? v : expm1f(v);    // ELU
        int g = batch[node];
        atomicAdd(&pooled[g * 16 + c], v);
        if (c == 0) atomicAdd(&counts[g], 1.0f);
    }
}

// ---------------- final: mean + linear classifier ----------------
__global__ __launch_bounds__(256) void k_final(
    const float* __restrict__ pooled, const float* __restrict__ counts,
    const float* __restrict__ Wc, const float* __restrict__ bc,
    float* __restrict__ out)
{
    int g = blockIdx.x * 256 + threadIdx.x;
    if (g >= NG) return;
    float cnt = fmaxf(counts[g], 1.0f);
    float acc = 0.f;
#pragma unroll
    for (int c = 0; c < 16; ++c) acc = fmaf(pooled[g * 16 + c] / cnt, Wc[c], acc);
    out[g] = acc + bc[0];
}

extern "C" void kernel_launch(void* const* d_in, const int* in_sizes, int n_in,
                              void* d_out, int out_size, void* d_ws, size_t ws_size,
                              hipStream_t stream)
{
    const float* x    = (const float*)d_in[0];
    const int*   ei   = (const int*)d_in[1];
    const int*   batc = (const int*)d_in[2];
    const float* W1   = (const float*)d_in[3];
    const float* a1s  = (const float*)d_in[4];
    const float* a1d  = (const float*)d_in[5];
    const float* b1   = (const float*)d_in[6];
    const float* W2   = (const float*)d_in[7];
    const float* a2s  = (const float*)d_in[8];
    const float* a2d  = (const float*)d_in[9];
    const float* b2   = (const float*)d_in[10];
    const float* Wc   = (const float*)d_in[11];
    const float* bc   = (const float*)d_in[12];
    float* out = (float*)d_out;

    // ---- workspace carve, 16B-aligned chunks. Zero region first, one memset. ----
    char* ws = (char*)d_ws;
    size_t off = 0;
    auto carve = [&](size_t elems) {
        void* p = ws + off;
        off += ((elems * 4 + 15) & ~(size_t)15);
        return p;
    };
    int*   deg    = (int*)  carve(N_NODES);        // zeroed
    float* pooled = (float*)carve((size_t)NG * 16);// zeroed
    float* counts = (float*)carve(NG);             // zeroed
    size_t zero_bytes = off;
    int*   part   = (int*)  carve(N_NODES);
    int*   bsum   = (int*)  carve(256);
    int*   offs   = (int*)  carve(N_NODES);
    int*   cursor = (int*)  carve(N_NODES);
    int*   csr    = (int*)  carve(ET);
    float* h1     = (float*)carve((size_t)N_NODES * 64);
    float* al1s   = (float*)carve((size_t)N_NODES * 4);
    float* al1d   = (float*)carve((size_t)N_NODES * 4);
    float* h2     = (float*)carve((size_t)N_NODES * 16);
    float* al2s   = (float*)carve(N_NODES);
    float* al2d   = (float*)carve(N_NODES);

    hipMemsetAsync(d_ws, 0, zero_bytes, stream);

    k_h1     <<<N_NODES / 4, 256, 0, stream>>>(x, W1, a1s, a1d, h1, al1s, al1d);
    k_hist   <<<(ET + 255) / 256, 256, 0, stream>>>(ei, deg);
    k_scan1  <<<NB_SCAN, 512, 0, stream>>>(deg, part, bsum);
    k_scan2  <<<1, 256, 0, stream>>>(bsum);
    k_scan3  <<<NB_SCAN, 512, 0, stream>>>(part, bsum, offs, cursor);
    k_scatter<<<(ET + 255) / 256, 256, 0, stream>>>(ei, cursor, csr);
    k_agg1   <<<N_NODES / 4, 256, 0, stream>>>(offs, deg, csr, h1, al1s, al1d,
                                               b1, W2, a2s, a2d, h2, al2s, al2d);
    k_agg2   <<<N_NODES / 4, 256, 0, stream>>>(offs, deg, csr, h2, al2s, al2d,
                                               b2, batc, pooled, counts);
    k_final  <<<(NG + 255) / 256, 256, 0, stream>>>(pooled, counts, Wc, bc, out);
}

// Round 5
// 486.980 us; speedup vs baseline: 1.4187x; 1.4187x over previous
//
#include <hip/hip_runtime.h>

#define N_NODES 100000
#define N_EDGES 1600000
#define ET      (N_EDGES + N_NODES)   // edges + self-loops = 1,700,000
#define NG      512
#define SLOPE   0.2f
#define NB_SCAN ((N_NODES + 511) / 512)   // 196 scan blocks

// ---------------- layer 1: h1 = x @ W1, attention logits ----------------
__global__ __launch_bounds__(256) void k_h1(
    const float* __restrict__ x, const float* __restrict__ W1,
    const float* __restrict__ a1s, const float* __restrict__ a1d,
    float* __restrict__ h1, float* __restrict__ al1s, float* __restrict__ al1d)
{
    __shared__ float Wl[64 * 64];
    __shared__ float xs[4][64];
    __shared__ float hs[4][64];
    int tid = threadIdx.x;
    for (int i = tid; i < 64 * 64; i += 256) Wl[i] = W1[i];
    int n = tid >> 6, c = tid & 63;
    int node = blockIdx.x * 4 + n;
    xs[n][c] = x[node * 64 + c];
    __syncthreads();
    float acc = 0.f;
#pragma unroll
    for (int k = 0; k < 64; ++k) acc = fmaf(xs[n][k], Wl[k * 64 + c], acc);
    h1[node * 64 + c] = acc;
    hs[n][c] = acc;
    __syncthreads();
    if (tid < 16) {
        int n2 = tid >> 2, h = tid & 3;
        int node2 = blockIdx.x * 4 + n2;
        float s = 0.f, d = 0.f;
#pragma unroll
        for (int j = 0; j < 16; ++j) {
            float v = hs[n2][h * 16 + j];
            s = fmaf(v, a1s[h * 16 + j], s);
            d = fmaf(v, a1d[h * 16 + j], d);
        }
        al1s[node2 * 4 + h] = s;
        al1d[node2 * 4 + h] = d;
    }
}

// ---------------- CSR build ----------------
__global__ __launch_bounds__(256) void k_hist(const int* __restrict__ ei, int* __restrict__ deg)
{
    int eid = blockIdx.x * 256 + threadIdx.x;
    if (eid >= ET) return;
    int d = (eid < N_EDGES) ? ei[N_EDGES + eid] : (eid - N_EDGES);
    atomicAdd(&deg[d], 1);
}

__global__ __launch_bounds__(512) void k_scan1(const int* __restrict__ deg,
                                               int* __restrict__ part, int* __restrict__ bsum)
{
    __shared__ int tmp[512];
    int i = blockIdx.x * 512 + threadIdx.x;
    int v = (i < N_NODES) ? deg[i] : 0;
    tmp[threadIdx.x] = v;
    __syncthreads();
    for (int off = 1; off < 512; off <<= 1) {
        int t = (threadIdx.x >= off) ? tmp[threadIdx.x - off] : 0;
        __syncthreads();
        tmp[threadIdx.x] += t;
        __syncthreads();
    }
    if (i < N_NODES) part[i] = tmp[threadIdx.x] - v;
    if (threadIdx.x == 511) bsum[blockIdx.x] = tmp[511];
}

__global__ __launch_bounds__(256) void k_scan2(int* __restrict__ bsum)
{
    __shared__ int tmp[256];
    int tid = threadIdx.x;
    int v = (tid < NB_SCAN) ? bsum[tid] : 0;
    tmp[tid] = v;
    __syncthreads();
    for (int off = 1; off < 256; off <<= 1) {
        int t = (tid >= off) ? tmp[tid - off] : 0;
        __syncthreads();
        tmp[tid] += t;
        __syncthreads();
    }
    if (tid < NB_SCAN) bsum[tid] = tmp[tid] - v;
}

__global__ __launch_bounds__(512) void k_scan3(const int* __restrict__ part,
                                               const int* __restrict__ bsum,
                                               int* __restrict__ offs, int* __restrict__ cursor)
{
    int i = blockIdx.x * 512 + threadIdx.x;
    if (i >= N_NODES) return;
    int o = part[i] + bsum[blockIdx.x];
    offs[i] = o;
    cursor[i] = o;
}

__global__ __launch_bounds__(256) void k_scatter(const int* __restrict__ ei,
                                                 int* __restrict__ cursor, int* __restrict__ csr)
{
    int eid = blockIdx.x * 256 + threadIdx.x;
    if (eid >= ET) return;
    int s, d;
    if (eid < N_EDGES) { s = ei[eid]; d = ei[N_EDGES + eid]; }
    else               { s = eid - N_EDGES; d = s; }
    int pos = atomicAdd(&cursor[d], 1);
    csr[pos] = s;
}

// ---- graph ranges from sorted batch ----
__global__ __launch_bounds__(256) void k_bound(const int* __restrict__ batch,
                                               int* __restrict__ gstart, int* __restrict__ gend)
{
    int i = blockIdx.x * 256 + threadIdx.x;
    if (i >= N_NODES) return;
    int b = batch[i];
    if (i == 0 || batch[i - 1] != b) gstart[b] = i;
    if (i == N_NODES - 1 || batch[i + 1] != b) gend[b] = i + 1;
}

// ---- layer 1 aggregate (1 wave/dst) + ELU + layer-2 linear + logits ----
__global__ __launch_bounds__(256) void k_agg1(
    const int* __restrict__ offs, const int* __restrict__ deg, const int* __restrict__ csr,
    const float* __restrict__ h1, const float* __restrict__ al1s, const float* __restrict__ al1d,
    const float* __restrict__ b1, const float* __restrict__ W2,
    const float* __restrict__ a2s, const float* __restrict__ a2d,
    float* __restrict__ h2, float* __restrict__ al2s, float* __restrict__ al2d)
{
    __shared__ float W2l[64 * 16];
    __shared__ int   sarr[4][64];
    __shared__ float warr[4][4 * 65];   // [wave][head*65 + j], padded: conflict-free
    __shared__ float h1b[4][64];
    __shared__ float h2s[4][16];
    int tid = threadIdx.x;
    for (int i = tid; i < 64 * 16; i += 256) W2l[i] = W2[i];
    __syncthreads();                    // only barrier: W2l is cross-wave

    int wv = tid >> 6, lane = tid & 63;
    int c = lane, h = lane >> 4;
    int node = blockIdx.x * 4 + wv;
    int st = offs[node], dg = deg[node];
    const float4 ald4 = *(const float4*)(al1d + node * 4);

    float acc = 0.f, den = 0.f;
    for (int base = 0; base < dg; base += 64) {
        int m = min(64, dg - base);
        if (lane < m) {
            int s = csr[st + base + lane];          // coalesced
            sarr[wv][lane] = s;
            const float4 as4 = *(const float4*)(al1s + s * 4);  // 16B gather
            float e0 = as4.x + ald4.x; e0 = e0 > 0.f ? e0 : SLOPE * e0;
            float e1 = as4.y + ald4.y; e1 = e1 > 0.f ? e1 : SLOPE * e1;
            float e2 = as4.z + ald4.z; e2 = e2 > 0.f ? e2 : SLOPE * e2;
            float e3 = as4.w + ald4.w; e3 = e3 > 0.f ? e3 : SLOPE * e3;
            warr[wv][0 * 65 + lane] = __expf(e0);
            warr[wv][1 * 65 + lane] = __expf(e1);
            warr[wv][2 * 65 + lane] = __expf(e2);
            warr[wv][3 * 65 + lane] = __expf(e3);
        }
        // intra-wave LDS dependency only — no barrier (trip counts diverge per wave)
#pragma unroll 4
        for (int j = 0; j < m; ++j) {
            int s = sarr[wv][j];                    // broadcast
            float wgt = warr[wv][h * 65 + j];       // broadcast per head
            acc = fmaf(wgt, h1[s * 64 + c], acc);   // 256B coalesced gather
            den += wgt;
        }
    }
    float v = acc / (den + 1e-16f) + b1[c];
    v = v > 0.f ? v : expm1f(v);        // ELU
    h1b[wv][c] = v;
    // intra-wave: no barrier needed
    if (c < 16) {
        float a = 0.f;
#pragma unroll
        for (int k = 0; k < 64; ++k) a = fmaf(h1b[wv][k], W2l[k * 16 + c], a);
        h2[node * 16 + c] = a;
        h2s[wv][c] = a;
    }
    if (c == 0) {
        float s2 = 0.f, d2 = 0.f;
#pragma unroll
        for (int j = 0; j < 16; ++j) {
            float v2 = h2s[wv][j];
            s2 = fmaf(v2, a2s[j], s2);
            d2 = fmaf(v2, a2d[j], d2);
        }
        al2s[node] = s2;
        al2d[node] = d2;
    }
}

// ---- layer 2 aggregate (1 wave/dst) + norm+ELU, NO atomics: write hout ----
__global__ __launch_bounds__(256) void k_agg2(
    const int* __restrict__ offs, const int* __restrict__ deg, const int* __restrict__ csr,
    const float* __restrict__ h2, const float* __restrict__ al2s, const float* __restrict__ al2d,
    const float* __restrict__ b2, float* __restrict__ hout)
{
    __shared__ int   sarr[4][64];
    __shared__ float warr[4][64];
    int tid = threadIdx.x;
    int wv = tid >> 6, lane = tid & 63;
    int sub = lane >> 4, c = lane & 15;
    int node = blockIdx.x * 4 + wv;
    int st = offs[node], dg = deg[node];
    float ald = al2d[node];

    float acc = 0.f, den = 0.f;
    for (int base = 0; base < dg; base += 64) {
        int m = min(64, dg - base);
        float wl = 0.f;
        if (lane < m) {
            int s = csr[st + base + lane];          // coalesced
            sarr[wv][lane] = s;
            float e = al2s[s] + ald;                // 64 independent gathers
            e = e > 0.f ? e : SLOPE * e;
            wl = __expf(e);
            warr[wv][lane] = wl;
        }
        float t = wl;
        t += __shfl_xor(t, 1);  t += __shfl_xor(t, 2);
        t += __shfl_xor(t, 4);  t += __shfl_xor(t, 8);
        t += __shfl_xor(t, 16); t += __shfl_xor(t, 32);
        den += t;
#pragma unroll 4
        for (int j = sub; j < m; j += 4) {
            int s = sarr[wv][j];                    // 16-lane broadcast
            float wgt = warr[wv][j];
            acc = fmaf(wgt, h2[s * 16 + c], acc);   // 64B gather x4 edges
        }
    }
    acc += __shfl_xor(acc, 16); acc += __shfl_xor(acc, 32);
    if (sub == 0) {
        float v = acc / (den + 1e-16f) + b2[c];
        v = v > 0.f ? v : expm1f(v);    // ELU
        hout[node * 16 + c] = v;        // coalesced, no atomics
    }
}

// ---- mean-pool per graph (contiguous node range) + classifier ----
__global__ __launch_bounds__(256) void k_pool(
    const float* __restrict__ hout, const int* __restrict__ gstart, const int* __restrict__ gend,
    const float* __restrict__ Wc, const float* __restrict__ bc, float* __restrict__ out)
{
    __shared__ float red[16][17];
    int g = blockIdx.x;
    int t = threadIdx.x, c = t & 15, slot = t >> 4;
    int s = gstart[g], e = gend[g];
    float sum = 0.f;
    for (int n = s + slot; n < e; n += 16)
        sum += hout[n * 16 + c];        // fully coalesced (1 KB / iter / block)
    red[slot][c] = sum;
    __syncthreads();
    if (t < 16) {                       // t == c, lanes 0..15 of wave 0
        float tot = 0.f;
#pragma unroll
        for (int k = 0; k < 16; ++k) tot += red[k][t];
        float cnt = fmaxf((float)(e - s), 1.0f);
        float pc = (tot / cnt) * Wc[t];
        pc += __shfl_xor(pc, 1); pc += __shfl_xor(pc, 2);
        pc += __shfl_xor(pc, 4); pc += __shfl_xor(pc, 8);
        if (t == 0) out[g] = pc + bc[0];
    }
}

extern "C" void kernel_launch(void* const* d_in, const int* in_sizes, int n_in,
                              void* d_out, int out_size, void* d_ws, size_t ws_size,
                              hipStream_t stream)
{
    const float* x    = (const float*)d_in[0];
    const int*   ei   = (const int*)d_in[1];
    const int*   batc = (const int*)d_in[2];
    const float* W1   = (const float*)d_in[3];
    const float* a1s  = (const float*)d_in[4];
    const float* a1d  = (const float*)d_in[5];
    const float* b1   = (const float*)d_in[6];
    const float* W2   = (const float*)d_in[7];
    const float* a2s  = (const float*)d_in[8];
    const float* a2d  = (const float*)d_in[9];
    const float* b2   = (const float*)d_in[10];
    const float* Wc   = (const float*)d_in[11];
    const float* bc   = (const float*)d_in[12];
    float* out = (float*)d_out;

    // ---- workspace carve, 16B-aligned chunks. Zero region first, one memset. ----
    char* ws = (char*)d_ws;
    size_t off = 0;
    auto carve = [&](size_t elems) {
        void* p = ws + off;
        off += ((elems * 4 + 15) & ~(size_t)15);
        return p;
    };
    int*   deg    = (int*)  carve(N_NODES);        // zeroed
    int*   gstart = (int*)  carve(NG);             // zeroed (empty graphs)
    int*   gend   = (int*)  carve(NG);             // zeroed
    size_t zero_bytes = off;
    int*   part   = (int*)  carve(N_NODES);
    int*   bsum   = (int*)  carve(256);
    int*   offs   = (int*)  carve(N_NODES);
    int*   cursor = (int*)  carve(N_NODES);
    int*   csr    = (int*)  carve(ET);
    float* h1     = (float*)carve((size_t)N_NODES * 64);
    float* al1s   = (float*)carve((size_t)N_NODES * 4);
    float* al1d   = (float*)carve((size_t)N_NODES * 4);
    float* h2     = (float*)carve((size_t)N_NODES * 16);
    float* al2s   = (float*)carve(N_NODES);
    float* al2d   = (float*)carve(N_NODES);
    float* hout   = (float*)carve((size_t)N_NODES * 16);

    hipMemsetAsync(d_ws, 0, zero_bytes, stream);

    k_h1     <<<N_NODES / 4, 256, 0, stream>>>(x, W1, a1s, a1d, h1, al1s, al1d);
    k_hist   <<<(ET + 255) / 256, 256, 0, stream>>>(ei, deg);
    k_scan1  <<<NB_SCAN, 512, 0, stream>>>(deg, part, bsum);
    k_scan2  <<<1, 256, 0, stream>>>(bsum);
    k_scan3  <<<NB_SCAN, 512, 0, stream>>>(part, bsum, offs, cursor);
    k_scatter<<<(ET + 255) / 256, 256, 0, stream>>>(ei, cursor, csr);
    k_bound  <<<(N_NODES + 255) / 256, 256, 0, stream>>>(batc, gstart, gend);
    k_agg1   <<<N_NODES / 4, 256, 0, stream>>>(offs, deg, csr, h1, al1s, al1d,
                                               b1, W2, a2s, a2d, h2, al2s, al2d);
    k_agg2   <<<N_NODES / 4, 256, 0, stream>>>(offs, deg, csr, h2, al2s, al2d,
                                               b2, hout);
    k_pool   <<<NG, 256, 0, stream>>>(hout, gstart, gend, Wc, bc, out);
}

// Round 6
// 372.863 us; speedup vs baseline: 1.8529x; 1.3061x over previous
//
#include <hip/hip_runtime.h>

#define N_NODES 100000
#define N_EDGES 1600000
#define ET      (N_EDGES + N_NODES)   // edges + self-loops = 1,700,000
#define NG      512
#define SLOPE   0.2f

#define BKT_SHIFT 9                         // 512 nodes per bucket
#define NB_B   ((N_NODES + 511) / 512)      // 196 buckets
#define CHUNK_A 8192
#define NBLK_A ((ET + CHUNK_A - 1) / CHUNK_A)   // 208

// ---------------- layer 1: h1 = x @ W1, attention logits ----------------
__global__ __launch_bounds__(256) void k_h1(
    const float* __restrict__ x, const float* __restrict__ W1,
    const float* __restrict__ a1s, const float* __restrict__ a1d,
    float* __restrict__ h1, float* __restrict__ al1s, float* __restrict__ al1d)
{
    __shared__ float Wl[64 * 64];
    __shared__ float xs[4][64];
    __shared__ float hs[4][64];
    int tid = threadIdx.x;
    for (int i = tid; i < 64 * 64; i += 256) Wl[i] = W1[i];
    int n = tid >> 6, c = tid & 63;
    int node = blockIdx.x * 4 + n;
    xs[n][c] = x[node * 64 + c];
    __syncthreads();
    float acc = 0.f;
#pragma unroll
    for (int k = 0; k < 64; ++k) acc = fmaf(xs[n][k], Wl[k * 64 + c], acc);
    h1[node * 64 + c] = acc;
    hs[n][c] = acc;
    __syncthreads();
    if (tid < 16) {
        int n2 = tid >> 2, h = tid & 3;
        int node2 = blockIdx.x * 4 + n2;
        float s = 0.f, d = 0.f;
#pragma unroll
        for (int j = 0; j < 16; ++j) {
            float v = hs[n2][h * 16 + j];
            s = fmaf(v, a1s[h * 16 + j], s);
            d = fmaf(v, a1d[h * 16 + j], d);
        }
        al1s[node2 * 4 + h] = s;
        al1d[node2 * 4 + h] = d;
    }
}

// ---------------- coarse bucket histogram (196 bins) ----------------
__global__ __launch_bounds__(256) void k_histA(const int* __restrict__ ei, int* __restrict__ bsize)
{
    __shared__ int h[NB_B];
    int tid = threadIdx.x;
    for (int i = tid; i < NB_B; i += 256) h[i] = 0;
    __syncthreads();
    int base = blockIdx.x * CHUNK_A;
    int m = min(CHUNK_A, ET - base);
    for (int i = tid; i < m; i += 256) {
        int eid = base + i;
        int d = (eid < N_EDGES) ? ei[N_EDGES + eid] : (eid - N_EDGES);
        atomicAdd(&h[d >> BKT_SHIFT], 1);
    }
    __syncthreads();
    for (int i = tid; i < NB_B; i += 256)
        if (h[i]) atomicAdd(&bsize[i], h[i]);
}

// ---------------- scan of bucket sizes (1 block) ----------------
__global__ __launch_bounds__(256) void k_scanB(const int* __restrict__ bsize,
                                               int* __restrict__ bbase, int* __restrict__ bcur)
{
    __shared__ int tmp[256];
    int tid = threadIdx.x;
    int v = (tid < NB_B) ? bsize[tid] : 0;
    tmp[tid] = v;
    __syncthreads();
    for (int off = 1; off < 256; off <<= 1) {
        int t = (tid >= off) ? tmp[tid - off] : 0;
        __syncthreads();
        tmp[tid] += t;
        __syncthreads();
    }
    if (tid < NB_B) { int e = tmp[tid] - v; bbase[tid] = e; bcur[tid] = e; }
}

// ---- pass A: LDS counting sort of 8K-edge chunks into bucket runs ----
__global__ __launch_bounds__(256) void k_passA(const int* __restrict__ ei,
                                               int* __restrict__ bcur, unsigned int* __restrict__ ebuf)
{
    __shared__ unsigned int stage[CHUNK_A];     // 32 KB
    __shared__ unsigned char sbin[CHUNK_A];     // 8 KB
    __shared__ int hist[NB_B];
    __shared__ int binst[NB_B];
    __shared__ int resv[NB_B];
    __shared__ int cur[NB_B];
    __shared__ int tmp[256];
    int tid = threadIdx.x;
    int base = blockIdx.x * CHUNK_A;
    int m = min(CHUNK_A, ET - base);
    for (int i = tid; i < NB_B; i += 256) hist[i] = 0;
    __syncthreads();
    for (int i = tid; i < m; i += 256) {
        int eid = base + i;
        int d = (eid < N_EDGES) ? ei[N_EDGES + eid] : (eid - N_EDGES);
        atomicAdd(&hist[d >> BKT_SHIFT], 1);
    }
    __syncthreads();
    // exclusive scan of the 196 bins + per-bin global reservation
    int v = (tid < NB_B) ? hist[tid] : 0;
    tmp[tid] = v;
    __syncthreads();
    for (int off = 1; off < 256; off <<= 1) {
        int t = (tid >= off) ? tmp[tid - off] : 0;
        __syncthreads();
        tmp[tid] += t;
        __syncthreads();
    }
    if (tid < NB_B) {
        int e = tmp[tid] - v;
        binst[tid] = e;
        cur[tid] = e;
        resv[tid] = v ? atomicAdd(&bcur[tid], v) : 0;   // ~196 atomics / block
    }
    __syncthreads();
    // place edges into bucket-sorted LDS order
    for (int i = tid; i < m; i += 256) {
        int eid = base + i;
        int s, d;
        if (eid < N_EDGES) { s = ei[eid]; d = ei[N_EDGES + eid]; }
        else               { s = eid - N_EDGES; d = s; }
        int b = d >> BKT_SHIFT;
        int pos = atomicAdd(&cur[b], 1);
        stage[pos] = ((unsigned int)(d & 511) << 17) | (unsigned int)s;
        sbin[pos] = (unsigned char)b;
    }
    __syncthreads();
    // write out: consecutive i within a bin run -> consecutive global addrs
    for (int i = tid; i < m; i += 256) {
        int b = sbin[i];
        ebuf[resv[b] + (i - binst[b])] = stage[i];
    }
}

// ---- pass B: per-bucket node hist+scan (-> deg/offs) + csr scatter ----
__global__ __launch_bounds__(256) void k_passB(
    const unsigned int* __restrict__ ebuf, const int* __restrict__ bbase,
    const int* __restrict__ bsize,
    int* __restrict__ csr, int* __restrict__ offs, int* __restrict__ deg)
{
    __shared__ int ldeg[512];
    __shared__ int lofs[512];
    __shared__ int lcur[512];
    int tid = threadIdx.x;
    int b = blockIdx.x;
    int nb0 = b << BKT_SHIFT;
    int nn = min(512, N_NODES - nb0);
    int gbase = bbase[b], cnt = bsize[b];
    for (int i = tid; i < 512; i += 256) ldeg[i] = 0;
    __syncthreads();
    for (int i = tid; i < cnt; i += 256)
        atomicAdd(&ldeg[ebuf[gbase + i] >> 17], 1);
    __syncthreads();
    int i0 = tid, i1 = tid + 256;
    int v0 = ldeg[i0], v1 = ldeg[i1];
    lofs[i0] = v0; lofs[i1] = v1;
    __syncthreads();
    for (int off = 1; off < 512; off <<= 1) {
        int t0 = (i0 >= off) ? lofs[i0 - off] : 0;
        int t1 = (i1 >= off) ? lofs[i1 - off] : 0;
        __syncthreads();
        lofs[i0] += t0; lofs[i1] += t1;
        __syncthreads();
    }
    int e0 = lofs[i0] - v0, e1 = lofs[i1] - v1;   // exclusive
    __syncthreads();
    lofs[i0] = e0; lofs[i1] = e1;
    lcur[i0] = e0; lcur[i1] = e1;
    __syncthreads();
    if (i0 < nn) { offs[nb0 + i0] = gbase + e0; deg[nb0 + i0] = v0; }
    if (i1 < nn) { offs[nb0 + i1] = gbase + e1; deg[nb0 + i1] = v1; }
    // scatter within this block's private contiguous csr region (single XCD:
    // L2 merges partial lines, writeback ~= region size)
    for (int i = tid; i < cnt; i += 256) {
        unsigned int e = ebuf[gbase + i];
        int dl = e >> 17, s = (int)(e & 0x1FFFF);
        int p = atomicAdd(&lcur[dl], 1);
        csr[gbase + p] = s;
    }
}

// ---- graph ranges from sorted batch ----
__global__ __launch_bounds__(256) void k_bound(const int* __restrict__ batch,
                                               int* __restrict__ gstart, int* __restrict__ gend)
{
    int i = blockIdx.x * 256 + threadIdx.x;
    if (i >= N_NODES) return;
    int b = batch[i];
    if (i == 0 || batch[i - 1] != b) gstart[b] = i;
    if (i == N_NODES - 1 || batch[i + 1] != b) gend[b] = i + 1;
}

// ---- layer 1 aggregate (1 wave/dst) + ELU + layer-2 linear + logits ----
__global__ __launch_bounds__(256) void k_agg1(
    const int* __restrict__ offs, const int* __restrict__ deg, const int* __restrict__ csr,
    const float* __restrict__ h1, const float* __restrict__ al1s, const float* __restrict__ al1d,
    const float* __restrict__ b1, const float* __restrict__ W2,
    const float* __restrict__ a2s, const float* __restrict__ a2d,
    float* __restrict__ h2, float* __restrict__ al2s, float* __restrict__ al2d)
{
    __shared__ float W2l[64 * 16];
    __shared__ int   sarr[4][64];
    __shared__ float warr[4][4 * 65];   // [wave][head*65 + j], padded: conflict-free
    __shared__ float h1b[4][64];
    __shared__ float h2s[4][16];
    int tid = threadIdx.x;
    for (int i = tid; i < 64 * 16; i += 256) W2l[i] = W2[i];
    __syncthreads();                    // only barrier: W2l is cross-wave

    int wv = tid >> 6, lane = tid & 63;
    int c = lane, h = lane >> 4;
    int node = blockIdx.x * 4 + wv;
    int st = offs[node], dg = deg[node];
    const float4 ald4 = *(const float4*)(al1d + node * 4);

    float acc = 0.f, den = 0.f;
    for (int base = 0; base < dg; base += 64) {
        int m = min(64, dg - base);
        if (lane < m) {
            int s = csr[st + base + lane];          // coalesced
            sarr[wv][lane] = s;
            const float4 as4 = *(const float4*)(al1s + s * 4);  // 16B gather
            float e0 = as4.x + ald4.x; e0 = e0 > 0.f ? e0 : SLOPE * e0;
            float e1 = as4.y + ald4.y; e1 = e1 > 0.f ? e1 : SLOPE * e1;
            float e2 = as4.z + ald4.z; e2 = e2 > 0.f ? e2 : SLOPE * e2;
            float e3 = as4.w + ald4.w; e3 = e3 > 0.f ? e3 : SLOPE * e3;
            warr[wv][0 * 65 + lane] = __expf(e0);
            warr[wv][1 * 65 + lane] = __expf(e1);
            warr[wv][2 * 65 + lane] = __expf(e2);
            warr[wv][3 * 65 + lane] = __expf(e3);
        }
        // intra-wave LDS dependency only — no barrier (trip counts diverge per wave)
#pragma unroll 4
        for (int j = 0; j < m; ++j) {
            int s = sarr[wv][j];                    // broadcast
            float wgt = warr[wv][h * 65 + j];       // broadcast per head
            acc = fmaf(wgt, h1[s * 64 + c], acc);   // 256B coalesced gather
            den += wgt;
        }
    }
    float v = acc / (den + 1e-16f) + b1[c];
    v = v > 0.f ? v : expm1f(v);        // ELU
    h1b[wv][c] = v;
    // intra-wave: no barrier needed
    if (c < 16) {
        float a = 0.f;
#pragma unroll
        for (int k = 0; k < 64; ++k) a = fmaf(h1b[wv][k], W2l[k * 16 + c], a);
        h2[node * 16 + c] = a;
        h2s[wv][c] = a;
    }
    if (c == 0) {
        float s2 = 0.f, d2 = 0.f;
#pragma unroll
        for (int j = 0; j < 16; ++j) {
            float v2 = h2s[wv][j];
            s2 = fmaf(v2, a2s[j], s2);
            d2 = fmaf(v2, a2d[j], d2);
        }
        al2s[node] = s2;
        al2d[node] = d2;
    }
}

// ---- layer 2 aggregate (1 wave/dst) + norm+ELU, NO atomics: write hout ----
__global__ __launch_bounds__(256) void k_agg2(
    const int* __restrict__ offs, const int* __restrict__ deg, const int* __restrict__ csr,
    const float* __restrict__ h2, const float* __restrict__ al2s, const float* __restrict__ al2d,
    const float* __restrict__ b2, float* __restrict__ hout)
{
    __shared__ int   sarr[4][64];
    __shared__ float warr[4][64];
    int tid = threadIdx.x;
    int wv = tid >> 6, lane = tid & 63;
    int sub = lane >> 4, c = lane & 15;
    int node = blockIdx.x * 4 + wv;
    int st = offs[node], dg = deg[node];
    float ald = al2d[node];

    float acc = 0.f, den = 0.f;
    for (int base = 0; base < dg; base += 64) {
        int m = min(64, dg - base);
        float wl = 0.f;
        if (lane < m) {
            int s = csr[st + base + lane];          // coalesced
            sarr[wv][lane] = s;
            float e = al2s[s] + ald;                // 64 independent gathers
            e = e > 0.f ? e : SLOPE * e;
            wl = __expf(e);
            warr[wv][lane] = wl;
        }
        float t = wl;
        t += __shfl_xor(t, 1);  t += __shfl_xor(t, 2);
        t += __shfl_xor(t, 4);  t += __shfl_xor(t, 8);
        t += __shfl_xor(t, 16); t += __shfl_xor(t, 32);
        den += t;
#pragma unroll 4
        for (int j = sub; j < m; j += 4) {
            int s = sarr[wv][j];                    // 16-lane broadcast
            float wgt = warr[wv][j];
            acc = fmaf(wgt, h2[s * 16 + c], acc);   // 64B gather x4 edges
        }
    }
    acc += __shfl_xor(acc, 16); acc += __shfl_xor(acc, 32);
    if (sub == 0) {
        float v = acc / (den + 1e-16f) + b2[c];
        v = v > 0.f ? v : expm1f(v);    // ELU
        hout[node * 16 + c] = v;        // coalesced, no atomics
    }
}

// ---- mean-pool per graph (contiguous node range) + classifier ----
__global__ __launch_bounds__(256) void k_pool(
    const float* __restrict__ hout, const int* __restrict__ gstart, const int* __restrict__ gend,
    const float* __restrict__ Wc, const float* __restrict__ bc, float* __restrict__ out)
{
    __shared__ float red[16][17];
    int g = blockIdx.x;
    int t = threadIdx.x, c = t & 15, slot = t >> 4;
    int s = gstart[g], e = gend[g];
    float sum = 0.f;
    for (int n = s + slot; n < e; n += 16)
        sum += hout[n * 16 + c];        // fully coalesced (1 KB / iter / block)
    red[slot][c] = sum;
    __syncthreads();
    if (t < 16) {                       // t == c, lanes 0..15 of wave 0
        float tot = 0.f;
#pragma unroll
        for (int k = 0; k < 16; ++k) tot += red[k][t];
        float cnt = fmaxf((float)(e - s), 1.0f);
        float pc = (tot / cnt) * Wc[t];
        pc += __shfl_xor(pc, 1); pc += __shfl_xor(pc, 2);
        pc += __shfl_xor(pc, 4); pc += __shfl_xor(pc, 8);
        if (t == 0) out[g] = pc + bc[0];
    }
}

extern "C" void kernel_launch(void* const* d_in, const int* in_sizes, int n_in,
                              void* d_out, int out_size, void* d_ws, size_t ws_size,
                              hipStream_t stream)
{
    const float* x    = (const float*)d_in[0];
    const int*   ei   = (const int*)d_in[1];
    const int*   batc = (const int*)d_in[2];
    const float* W1   = (const float*)d_in[3];
    const float* a1s  = (const float*)d_in[4];
    const float* a1d  = (const float*)d_in[5];
    const float* b1   = (const float*)d_in[6];
    const float* W2   = (const float*)d_in[7];
    const float* a2s  = (const float*)d_in[8];
    const float* a2d  = (const float*)d_in[9];
    const float* b2   = (const float*)d_in[10];
    const float* Wc   = (const float*)d_in[11];
    const float* bc   = (const float*)d_in[12];
    float* out = (float*)d_out;

    // ---- workspace carve, 16B-aligned chunks. Zero region first, one memset. ----
    char* ws = (char*)d_ws;
    size_t off = 0;
    auto carve = [&](size_t elems) {
        void* p = ws + off;
        off += ((elems * 4 + 15) & ~(size_t)15);
        return p;
    };
    int*   bsize  = (int*)  carve(NB_B);           // zeroed
    int*   gstart = (int*)  carve(NG);             // zeroed (empty graphs)
    int*   gend   = (int*)  carve(NG);             // zeroed
    size_t zero_bytes = off;
    int*   bbase  = (int*)  carve(NB_B);
    int*   bcur   = (int*)  carve(NB_B);
    unsigned int* ebuf = (unsigned int*)carve(ET);
    int*   csr    = (int*)  carve(ET);
    int*   offs   = (int*)  carve(N_NODES);
    int*   deg    = (int*)  carve(N_NODES);
    float* h1     = (float*)carve((size_t)N_NODES * 64);
    float* al1s   = (float*)carve((size_t)N_NODES * 4);
    float* al1d   = (float*)carve((size_t)N_NODES * 4);
    float* h2     = (float*)carve((size_t)N_NODES * 16);
    float* al2s   = (float*)carve(N_NODES);
    float* al2d   = (float*)carve(N_NODES);
    float* hout   = (float*)carve((size_t)N_NODES * 16);

    hipMemsetAsync(d_ws, 0, zero_bytes, stream);

    k_h1   <<<N_NODES / 4, 256, 0, stream>>>(x, W1, a1s, a1d, h1, al1s, al1d);
    k_histA<<<NBLK_A, 256, 0, stream>>>(ei, bsize);
    k_scanB<<<1, 256, 0, stream>>>(bsize, bbase, bcur);
    k_passA<<<NBLK_A, 256, 0, stream>>>(ei, bcur, ebuf);
    k_passB<<<NB_B, 256, 0, stream>>>(ebuf, bbase, bsize, csr, offs, deg);
    k_bound<<<(N_NODES + 255) / 256, 256, 0, stream>>>(batc, gstart, gend);
    k_agg1 <<<N_NODES / 4, 256, 0, stream>>>(offs, deg, csr, h1, al1s, al1d,
                                             b1, W2, a2s, a2d, h2, al2s, al2d);
    k_agg2 <<<N_NODES / 4, 256, 0, stream>>>(offs, deg, csr, h2, al2s, al2d,
                                             b2, hout);
    k_pool <<<NG, 256, 0, stream>>>(hout, gstart, gend, Wc, bc, out);
}

// Round 7
// 359.346 us; speedup vs baseline: 1.9226x; 1.0376x over previous
//
#include <hip/hip_runtime.h>
#include <hip/hip_fp16.h>

#define N_NODES 100000
#define N_EDGES 1600000
#define ET      (N_EDGES + N_NODES)   // edges + self-loops = 1,700,000
#define NG      512
#define SLOPE   0.2f

#define BKT_SHIFT 9                         // 512 nodes per bucket
#define NB_B   ((N_NODES + 511) / 512)      // 196 buckets
#define CHUNK_A 8192
#define NBLK_A ((ET + CHUNK_A - 1) / CHUNK_A)   // 208

// ---------------- layer 1: h1 = x @ W1 (stored fp16), attention logits ----------------
__global__ __launch_bounds__(256) void k_h1(
    const float* __restrict__ x, const float* __restrict__ W1,
    const float* __restrict__ a1s, const float* __restrict__ a1d,
    __half* __restrict__ h1, float* __restrict__ al1s, float* __restrict__ al1d)
{
    __shared__ float Wl[64 * 64];
    __shared__ float xs[4][64];
    __shared__ float hs[4][64];
    int tid = threadIdx.x;
    for (int i = tid; i < 64 * 64; i += 256) Wl[i] = W1[i];
    int n = tid >> 6, c = tid & 63;
    int node = blockIdx.x * 4 + n;
    xs[n][c] = x[node * 64 + c];
    __syncthreads();
    float acc = 0.f;
#pragma unroll
    for (int k = 0; k < 64; ++k) acc = fmaf(xs[n][k], Wl[k * 64 + c], acc);
    h1[node * 64 + c] = __float2half_rn(acc);
    hs[n][c] = acc;
    __syncthreads();
    if (tid < 16) {
        int n2 = tid >> 2, h = tid & 3;
        int node2 = blockIdx.x * 4 + n2;
        float s = 0.f, d = 0.f;
#pragma unroll
        for (int j = 0; j < 16; ++j) {
            float v = hs[n2][h * 16 + j];
            s = fmaf(v, a1s[h * 16 + j], s);
            d = fmaf(v, a1d[h * 16 + j], d);
        }
        al1s[node2 * 4 + h] = s;
        al1d[node2 * 4 + h] = d;
    }
}

// ---------------- coarse bucket histogram (196 bins) ----------------
__global__ __launch_bounds__(256) void k_histA(const int* __restrict__ ei, int* __restrict__ bsize)
{
    __shared__ int h[NB_B];
    int tid = threadIdx.x;
    for (int i = tid; i < NB_B; i += 256) h[i] = 0;
    __syncthreads();
    int base = blockIdx.x * CHUNK_A;
    int m = min(CHUNK_A, ET - base);
    for (int i = tid; i < m; i += 256) {
        int eid = base + i;
        int d = (eid < N_EDGES) ? ei[N_EDGES + eid] : (eid - N_EDGES);
        atomicAdd(&h[d >> BKT_SHIFT], 1);
    }
    __syncthreads();
    for (int i = tid; i < NB_B; i += 256)
        if (h[i]) atomicAdd(&bsize[i], h[i]);
}

// ---------------- scan of bucket sizes (1 block) ----------------
__global__ __launch_bounds__(256) void k_scanB(const int* __restrict__ bsize,
                                               int* __restrict__ bbase, int* __restrict__ bcur)
{
    __shared__ int tmp[256];
    int tid = threadIdx.x;
    int v = (tid < NB_B) ? bsize[tid] : 0;
    tmp[tid] = v;
    __syncthreads();
    for (int off = 1; off < 256; off <<= 1) {
        int t = (tid >= off) ? tmp[tid - off] : 0;
        __syncthreads();
        tmp[tid] += t;
        __syncthreads();
    }
    if (tid < NB_B) { int e = tmp[tid] - v; bbase[tid] = e; bcur[tid] = e; }
}

// ---- pass A: LDS counting sort of 8K-edge chunks into bucket runs ----
__global__ __launch_bounds__(256) void k_passA(const int* __restrict__ ei,
                                               int* __restrict__ bcur, unsigned int* __restrict__ ebuf)
{
    __shared__ unsigned int stage[CHUNK_A];     // 32 KB
    __shared__ unsigned char sbin[CHUNK_A];     // 8 KB
    __shared__ int hist[NB_B];
    __shared__ int binst[NB_B];
    __shared__ int resv[NB_B];
    __shared__ int cur[NB_B];
    __shared__ int tmp[256];
    int tid = threadIdx.x;
    int base = blockIdx.x * CHUNK_A;
    int m = min(CHUNK_A, ET - base);
    for (int i = tid; i < NB_B; i += 256) hist[i] = 0;
    __syncthreads();
    for (int i = tid; i < m; i += 256) {
        int eid = base + i;
        int d = (eid < N_EDGES) ? ei[N_EDGES + eid] : (eid - N_EDGES);
        atomicAdd(&hist[d >> BKT_SHIFT], 1);
    }
    __syncthreads();
    // exclusive scan of the 196 bins + per-bin global reservation
    int v = (tid < NB_B) ? hist[tid] : 0;
    tmp[tid] = v;
    __syncthreads();
    for (int off = 1; off < 256; off <<= 1) {
        int t = (tid >= off) ? tmp[tid - off] : 0;
        __syncthreads();
        tmp[tid] += t;
        __syncthreads();
    }
    if (tid < NB_B) {
        int e = tmp[tid] - v;
        binst[tid] = e;
        cur[tid] = e;
        resv[tid] = v ? atomicAdd(&bcur[tid], v) : 0;   // ~196 atomics / block
    }
    __syncthreads();
    // place edges into bucket-sorted LDS order
    for (int i = tid; i < m; i += 256) {
        int eid = base + i;
        int s, d;
        if (eid < N_EDGES) { s = ei[eid]; d = ei[N_EDGES + eid]; }
        else               { s = eid - N_EDGES; d = s; }
        int b = d >> BKT_SHIFT;
        int pos = atomicAdd(&cur[b], 1);
        stage[pos] = ((unsigned int)(d & 511) << 17) | (unsigned int)s;
        sbin[pos] = (unsigned char)b;
    }
    __syncthreads();
    // write out: consecutive i within a bin run -> consecutive global addrs
    for (int i = tid; i < m; i += 256) {
        int b = sbin[i];
        ebuf[resv[b] + (i - binst[b])] = stage[i];
    }
}

// ---- pass B: per-bucket node hist+scan (-> deg/offs) + csr scatter ----
__global__ __launch_bounds__(256) void k_passB(
    const unsigned int* __restrict__ ebuf, const int* __restrict__ bbase,
    const int* __restrict__ bsize,
    int* __restrict__ csr, int* __restrict__ offs, int* __restrict__ deg)
{
    __shared__ int ldeg[512];
    __shared__ int lofs[512];
    __shared__ int lcur[512];
    int tid = threadIdx.x;
    int b = blockIdx.x;
    int nb0 = b << BKT_SHIFT;
    int nn = min(512, N_NODES - nb0);
    int gbase = bbase[b], cnt = bsize[b];
    for (int i = tid; i < 512; i += 256) ldeg[i] = 0;
    __syncthreads();
    for (int i = tid; i < cnt; i += 256)
        atomicAdd(&ldeg[ebuf[gbase + i] >> 17], 1);
    __syncthreads();
    int i0 = tid, i1 = tid + 256;
    int v0 = ldeg[i0], v1 = ldeg[i1];
    lofs[i0] = v0; lofs[i1] = v1;
    __syncthreads();
    for (int off = 1; off < 512; off <<= 1) {
        int t0 = (i0 >= off) ? lofs[i0 - off] : 0;
        int t1 = (i1 >= off) ? lofs[i1 - off] : 0;
        __syncthreads();
        lofs[i0] += t0; lofs[i1] += t1;
        __syncthreads();
    }
    int e0 = lofs[i0] - v0, e1 = lofs[i1] - v1;   // exclusive
    __syncthreads();
    lofs[i0] = e0; lofs[i1] = e1;
    lcur[i0] = e0; lcur[i1] = e1;
    __syncthreads();
    if (i0 < nn) { offs[nb0 + i0] = gbase + e0; deg[nb0 + i0] = v0; }
    if (i1 < nn) { offs[nb0 + i1] = gbase + e1; deg[nb0 + i1] = v1; }
    // scatter within this block's private contiguous csr region (single XCD:
    // L2 merges partial lines, writeback ~= region size)
    for (int i = tid; i < cnt; i += 256) {
        unsigned int e = ebuf[gbase + i];
        int dl = e >> 17, s = (int)(e & 0x1FFFF);
        int p = atomicAdd(&lcur[dl], 1);
        csr[gbase + p] = s;
    }
}

// ---- graph ranges from sorted batch ----
__global__ __launch_bounds__(256) void k_bound(const int* __restrict__ batch,
                                               int* __restrict__ gstart, int* __restrict__ gend)
{
    int i = blockIdx.x * 256 + threadIdx.x;
    if (i >= N_NODES) return;
    int b = batch[i];
    if (i == 0 || batch[i - 1] != b) gstart[b] = i;
    if (i == N_NODES - 1 || batch[i + 1] != b) gend[b] = i + 1;
}

// ---- layer 1 aggregate (1 wave/dst, fp16 h1 gathers) + ELU + layer-2 linear + logits ----
__global__ __launch_bounds__(256) void k_agg1(
    const int* __restrict__ offs, const int* __restrict__ deg, const int* __restrict__ csr,
    const __half* __restrict__ h1, const float* __restrict__ al1s, const float* __restrict__ al1d,
    const float* __restrict__ b1, const float* __restrict__ W2,
    const float* __restrict__ a2s, const float* __restrict__ a2d,
    float* __restrict__ h2, float* __restrict__ al2s, float* __restrict__ al2d)
{
    __shared__ float W2l[64 * 16];
    __shared__ int   sarr[4][64];
    __shared__ float warr[4][4 * 65];   // [wave][head*65 + j], padded: conflict-free
    __shared__ float h1b[4][64];
    __shared__ float h2s[4][16];
    int tid = threadIdx.x;
    for (int i = tid; i < 64 * 16; i += 256) W2l[i] = W2[i];
    __syncthreads();                    // only barrier: W2l is cross-wave

    int wv = tid >> 6, lane = tid & 63;
    int c = lane, h = lane >> 4;
    int node = blockIdx.x * 4 + wv;
    int st = offs[node], dg = deg[node];
    const float4 ald4 = *(const float4*)(al1d + node * 4);

    float acc = 0.f, den = 0.f;
    for (int base = 0; base < dg; base += 64) {
        int m = min(64, dg - base);
        if (lane < m) {
            int s = csr[st + base + lane];          // coalesced
            sarr[wv][lane] = s;
            const float4 as4 = *(const float4*)(al1s + s * 4);  // 16B gather (L2-resident)
            float e0 = as4.x + ald4.x; e0 = e0 > 0.f ? e0 : SLOPE * e0;
            float e1 = as4.y + ald4.y; e1 = e1 > 0.f ? e1 : SLOPE * e1;
            float e2 = as4.z + ald4.z; e2 = e2 > 0.f ? e2 : SLOPE * e2;
            float e3 = as4.w + ald4.w; e3 = e3 > 0.f ? e3 : SLOPE * e3;
            warr[wv][0 * 65 + lane] = __expf(e0);
            warr[wv][1 * 65 + lane] = __expf(e1);
            warr[wv][2 * 65 + lane] = __expf(e2);
            warr[wv][3 * 65 + lane] = __expf(e3);
        }
        // intra-wave LDS dependency only — no barrier (trip counts diverge per wave)
#pragma unroll 4
        for (int j = 0; j < m; ++j) {
            int s = sarr[wv][j];                    // broadcast
            float wgt = warr[wv][h * 65 + j];       // broadcast per head
            acc = fmaf(wgt, __half2float(h1[s * 64 + c]), acc);  // 128B coalesced gather
            den += wgt;
        }
    }
    float v = acc / (den + 1e-16f) + b1[c];
    v = v > 0.f ? v : expm1f(v);        // ELU
    h1b[wv][c] = v;
    // intra-wave: no barrier needed
    if (c < 16) {
        float a = 0.f;
#pragma unroll
        for (int k = 0; k < 64; ++k) a = fmaf(h1b[wv][k], W2l[k * 16 + c], a);
        h2[node * 16 + c] = a;
        h2s[wv][c] = a;
    }
    if (c == 0) {
        float s2 = 0.f, d2 = 0.f;
#pragma unroll
        for (int j = 0; j < 16; ++j) {
            float v2 = h2s[wv][j];
            s2 = fmaf(v2, a2s[j], s2);
            d2 = fmaf(v2, a2d[j], d2);
        }
        al2s[node] = s2;
        al2d[node] = d2;
    }
}

// ---- layer 2 aggregate (1 wave/dst) + norm+ELU, NO atomics: write hout ----
// h2 stays f32: 64B row == one sector, fetch-optimal for random per-edge gathers
__global__ __launch_bounds__(256) void k_agg2(
    const int* __restrict__ offs, const int* __restrict__ deg, const int* __restrict__ csr,
    const float* __restrict__ h2, const float* __restrict__ al2s, const float* __restrict__ al2d,
    const float* __restrict__ b2, float* __restrict__ hout)
{
    __shared__ int   sarr[4][64];
    __shared__ float warr[4][64];
    int tid = threadIdx.x;
    int wv = tid >> 6, lane = tid & 63;
    int sub = lane >> 4, c = lane & 15;
    int node = blockIdx.x * 4 + wv;
    int st = offs[node], dg = deg[node];
    float ald = al2d[node];

    float acc = 0.f, den = 0.f;
    for (int base = 0; base < dg; base += 64) {
        int m = min(64, dg - base);
        float wl = 0.f;
        if (lane < m) {
            int s = csr[st + base + lane];          // coalesced
            sarr[wv][lane] = s;
            float e = al2s[s] + ald;                // 64 independent gathers (L2-resident)
            e = e > 0.f ? e : SLOPE * e;
            wl = __expf(e);
            warr[wv][lane] = wl;
        }
        float t = wl;
        t += __shfl_xor(t, 1);  t += __shfl_xor(t, 2);
        t += __shfl_xor(t, 4);  t += __shfl_xor(t, 8);
        t += __shfl_xor(t, 16); t += __shfl_xor(t, 32);
        den += t;
#pragma unroll 4
        for (int j = sub; j < m; j += 4) {
            int s = sarr[wv][j];                    // 16-lane broadcast
            float wgt = warr[wv][j];
            acc = fmaf(wgt, h2[s * 16 + c], acc);   // 64B gather x4 edges
        }
    }
    acc += __shfl_xor(acc, 16); acc += __shfl_xor(acc, 32);
    if (sub == 0) {
        float v = acc / (den + 1e-16f) + b2[c];
        v = v > 0.f ? v : expm1f(v);    // ELU
        hout[node * 16 + c] = v;        // coalesced, no atomics
    }
}

// ---- mean-pool per graph (contiguous node range) + classifier ----
__global__ __launch_bounds__(256) void k_pool(
    const float* __restrict__ hout, const int* __restrict__ gstart, const int* __restrict__ gend,
    const float* __restrict__ Wc, const float* __restrict__ bc, float* __restrict__ out)
{
    __shared__ float red[16][17];
    int g = blockIdx.x;
    int t = threadIdx.x, c = t & 15, slot = t >> 4;
    int s = gstart[g], e = gend[g];
    float sum = 0.f;
    for (int n = s + slot; n < e; n += 16)
        sum += hout[n * 16 + c];        // fully coalesced (1 KB / iter / block)
    red[slot][c] = sum;
    __syncthreads();
    if (t < 16) {                       // t == c, lanes 0..15 of wave 0
        float tot = 0.f;
#pragma unroll
        for (int k = 0; k < 16; ++k) tot += red[k][t];
        float cnt = fmaxf((float)(e - s), 1.0f);
        float pc = (tot / cnt) * Wc[t];
        pc += __shfl_xor(pc, 1); pc += __shfl_xor(pc, 2);
        pc += __shfl_xor(pc, 4); pc += __shfl_xor(pc, 8);
        if (t == 0) out[g] = pc + bc[0];
    }
}

extern "C" void kernel_launch(void* const* d_in, const int* in_sizes, int n_in,
                              void* d_out, int out_size, void* d_ws, size_t ws_size,
                              hipStream_t stream)
{
    const float* x    = (const float*)d_in[0];
    const int*   ei   = (const int*)d_in[1];
    const int*   batc = (const int*)d_in[2];
    const float* W1   = (const float*)d_in[3];
    const float* a1s  = (const float*)d_in[4];
    const float* a1d  = (const float*)d_in[5];
    const float* b1   = (const float*)d_in[6];
    const float* W2   = (const float*)d_in[7];
    const float* a2s  = (const float*)d_in[8];
    const float* a2d  = (const float*)d_in[9];
    const float* b2   = (const float*)d_in[10];
    const float* Wc   = (const float*)d_in[11];
    const float* bc   = (const float*)d_in[12];
    float* out = (float*)d_out;

    // ---- workspace carve, 16B-aligned chunks. Zero region first, one memset. ----
    char* ws = (char*)d_ws;
    size_t off = 0;
    auto carveB = [&](size_t bytes) {
        void* p = ws + off;
        off += ((bytes + 15) & ~(size_t)15);
        return p;
    };
    auto carve = [&](size_t elems) { return carveB(elems * 4); };
    int*   bsize  = (int*)  carve(NB_B);           // zeroed
    int*   gstart = (int*)  carve(NG);             // zeroed (empty graphs)
    int*   gend   = (int*)  carve(NG);             // zeroed
    size_t zero_bytes = off;
    int*   bbase  = (int*)  carve(NB_B);
    int*   bcur   = (int*)  carve(NB_B);
    unsigned int* ebuf = (unsigned int*)carve(ET);
    int*   csr    = (int*)  carve(ET);
    int*   offs   = (int*)  carve(N_NODES);
    int*   deg    = (int*)  carve(N_NODES);
    __half* h1    = (__half*)carveB((size_t)N_NODES * 64 * 2);
    float* al1s   = (float*)carve((size_t)N_NODES * 4);
    float* al1d   = (float*)carve((size_t)N_NODES * 4);
    float* h2     = (float*)carve((size_t)N_NODES * 16);
    float* al2s   = (float*)carve(N_NODES);
    float* al2d   = (float*)carve(N_NODES);
    float* hout   = (float*)carve((size_t)N_NODES * 16);

    hipMemsetAsync(d_ws, 0, zero_bytes, stream);

    k_h1   <<<N_NODES / 4, 256, 0, stream>>>(x, W1, a1s, a1d, h1, al1s, al1d);
    k_histA<<<NBLK_A, 256, 0, stream>>>(ei, bsize);
    k_scanB<<<1, 256, 0, stream>>>(bsize, bbase, bcur);
    k_passA<<<NBLK_A, 256, 0, stream>>>(ei, bcur, ebuf);
    k_passB<<<NB_B, 256, 0, stream>>>(ebuf, bbase, bsize, csr, offs, deg);
    k_bound<<<(N_NODES + 255) / 256, 256, 0, stream>>>(batc, gstart, gend);
    k_agg1 <<<N_NODES / 4, 256, 0, stream>>>(offs, deg, csr, h1, al1s, al1d,
                                             b1, W2, a2s, a2d, h2, al2s, al2d);
    k_agg2 <<<N_NODES / 4, 256, 0, stream>>>(offs, deg, csr, h2, al2s, al2d,
                                             b2, hout);
    k_pool <<<NG, 256, 0, stream>>>(hout, gstart, gend, Wc, bc, out);
}